// Round 6
// baseline (370.222 us; speedup 1.0000x reference)
//
#include <hip/hip_runtime.h>

// GIN 2-layer, N=100000, E=1600000, D=128.
// R11: half-row (128B) sliced aggregation. Wave = (node, half); h =
// blockIdx&1 -> even/odd blocks land on even/odd XCDs (round-robin
// dispatch, mechanism validated by R9's FETCH drop), so each XCD caches
// only one 128B half of each row: per-XCD fill ~12.5MB vs 22MB -> FETCH
// ~190->~140MB. Quarter-wave still covers 2 full cache lines (2 edges x
// 128B) - R9's divergence mistake avoided. Adjacency padded to multiple
// of 8 (self + sentinel row n). Weights pre-converted to bf16 once
// (wcvt) - mlp blocks no longer re-read fp32 W or re-run f2b.

typedef __attribute__((ext_vector_type(8))) short bf16x8;
typedef __attribute__((ext_vector_type(4))) float floatx4;
typedef __attribute__((ext_vector_type(2))) float floatx2;
typedef __attribute__((ext_vector_type(4))) unsigned uintx4;

#define WS_ALIGN(x) (((x) + 255) & ~(size_t)255)
#define NBMAX 400   // max buckets (n <= 102400)
#define BCAP 6144   // per-bucket capacity (mean 4096, sd ~64)

__device__ __forceinline__ unsigned short f2b(float f) {  // RTNE fp32->bf16
  unsigned u = __builtin_bit_cast(unsigned, f);
  u = (u + 0x7FFF + ((u >> 16) & 1)) >> 16;
  return (unsigned short)u;
}

// unpack a dword of 2 bf16 into {lo,hi} as f32 pair
__device__ __forceinline__ floatx2 bpair(unsigned d) {
  floatx2 r;
  r[0] = __builtin_bit_cast(float, d << 16);
  r[1] = __builtin_bit_cast(float, d & 0xffff0000u);
  return r;
}

// ---------- phase A: multisplit edges into 256-node buckets ----------
__global__ __launch_bounds__(256) void bucket_split(const int* __restrict__ src,
                                                    const int* __restrict__ dst,
                                                    int* __restrict__ bcnt,
                                                    unsigned* __restrict__ barr, int E, int nb) {
  __shared__ int cnt[NBMAX], base[NBMAX], cur[NBMAX];
  int t = threadIdx.x;
  for (int i = t; i < nb; i += 256) { cnt[i] = 0; cur[i] = 0; }
  __syncthreads();
  int e0 = blockIdx.x * 8192;
  int s[32], d[32];
#pragma unroll
  for (int k = 0; k < 32; k++) {
    int e = e0 + k * 256 + t;
    if (e < E) { s[k] = src[e]; d[k] = dst[e]; } else { d[k] = -1; }
  }
#pragma unroll
  for (int k = 0; k < 32; k++)
    if (d[k] >= 0) atomicAdd(&cnt[d[k] >> 8], 1);
  __syncthreads();
  for (int i = t; i < nb; i += 256) base[i] = cnt[i] ? atomicAdd(&bcnt[i], cnt[i]) : 0;
  __syncthreads();
#pragma unroll
  for (int k = 0; k < 32; k++)
    if (d[k] >= 0) {
      int b = d[k] >> 8;
      int r = atomicAdd(&cur[b], 1);
      barr[(size_t)b * BCAP + base[b] + r] = ((unsigned)(d[k] & 255) << 17) | (unsigned)s[k];
    }
}

// ---------- phase B: scan bucket counts (+2048 pad room per bucket) ----------
__global__ void bucket_scan(const int* __restrict__ bcnt, int* __restrict__ sbase, int nb,
                            int* __restrict__ rowptr, int n) {
  __shared__ int buf[512];
  int t = threadIdx.x;
  int v = (t < nb) ? (bcnt[t] + 2048) : 0;  // worst-case per-node pad = 8
  buf[t] = v;
  __syncthreads();
  for (int off = 1; off < 512; off <<= 1) {
    int add = (t >= off) ? buf[t - off] : 0;
    __syncthreads();
    buf[t] += add;
    __syncthreads();
  }
  if (t < nb) sbase[t] = buf[t] - v;  // exclusive
  if (t == nb - 1) { sbase[nb] = buf[t]; rowptr[n] = buf[t]; }
}

// ---------- phase C: per-bucket CSR finalize with padding (mult of 8) ----------
// Per node: vp = ceil((cnt+1)/8)*8. Slots: [0,cnt) real edges, slot cnt =
// self node, rest = sentinel n (zero row). Gaps never referenced (degp).
__global__ __launch_bounds__(256) void bucket_csr(const unsigned* __restrict__ barr,
                                                  const int* __restrict__ bcnt,
                                                  const int* __restrict__ sbase,
                                                  int* __restrict__ rowptr,
                                                  int* __restrict__ degp,
                                                  int* __restrict__ srt, int n) {
  __shared__ int cnt[256], off[256], off2[256];
  int b = blockIdx.x, t = threadIdx.x;
  int cb = bcnt[b];
  int node0 = b * 256;
  int nlocal = min(256, n - node0);
  cnt[t] = 0;
  off2[t] = 0;
  __syncthreads();
  const unsigned* bp = barr + (size_t)b * BCAP;
  for (int i = t; i < cb; i += 256) atomicAdd(&cnt[bp[i] >> 17], 1);
  __syncthreads();
  int v = cnt[t];                 // real edge count
  int vp = (v + 8) & ~7;          // padded: self + sentinels, mult of 8
  off[t] = vp;
  __syncthreads();
  for (int o = 1; o < 256; o <<= 1) {
    int add = (t >= o) ? off[t - o] : 0;
    __syncthreads();
    off[t] += add;
    __syncthreads();
  }
  int excl = off[t] - vp;
  int sb = sbase[b];
  if (t < nlocal) {
    rowptr[node0 + t] = sb + excl;
    degp[node0 + t] = vp;
  }
  cnt[t] = excl;
  __syncthreads();
  for (int i = t; i < cb; i += 256) {
    unsigned pk = bp[i];
    int local = pk >> 17;
    int r = atomicAdd(&off2[local], 1);
    srt[sb + cnt[local] + r] = pk & 0x1FFFF;
  }
  // pads: self then sentinels (disjoint positions, no sync needed)
  if (t < nlocal) {
    int base = sb + excl;
    srt[base + v] = node0 + t;                           // self term
    for (int i = v + 1; i < vp; i++) srt[base + i] = n;  // zero row
  }
}

// ---------- fp32 -> bf16 convert (row-major) ----------
__global__ void cvt_kernel(const float* __restrict__ x, unsigned short* __restrict__ xb, int n4) {
  int i = blockIdx.x * blockDim.x + threadIdx.x;
  if (i < n4) {
    float4 v = ((const float4*)x)[i];
    uint2 pk;
    pk.x = (unsigned)f2b(v.x) | ((unsigned)f2b(v.y) << 16);
    pk.y = (unsigned)f2b(v.z) | ((unsigned)f2b(v.w) << 16);
    ((uint2*)xb)[i] = pk;
  }
}

// ---------- weights fp32 -> bf16 (once) ----------
// 4 matrices of 128x128; out chunk i (8 bf16 = 16B) from floats [i*8, i*8+8).
__global__ __launch_bounds__(256) void wcvt_kernel(const float* __restrict__ w0,
                                                   const float* __restrict__ w1,
                                                   const float* __restrict__ w2,
                                                   const float* __restrict__ w3,
                                                   uintx4* __restrict__ out) {
  int i = blockIdx.x * 256 + threadIdx.x;  // 0..8191
  const float* W = (i < 2048) ? w0 : (i < 4096) ? w1 : (i < 6144) ? w2 : w3;
  int j = i & 2047;
  float4 a = ((const float4*)W)[j * 2];
  float4 b = ((const float4*)W)[j * 2 + 1];
  uintx4 pk;
  pk.x = (unsigned)f2b(a.x) | ((unsigned)f2b(a.y) << 16);
  pk.y = (unsigned)f2b(a.z) | ((unsigned)f2b(a.w) << 16);
  pk.z = (unsigned)f2b(b.x) | ((unsigned)f2b(b.y) << 16);
  pk.w = (unsigned)f2b(b.z) | ((unsigned)f2b(b.w) << 16);
  out[i] = pk;
}

// ---------- aggregation (bf16 in/out, fp32 accumulate, half-row sliced) ----------
// block b: h = b&1 (XCD-parity pinned half), nodes (b>>1)*4 + wave.
// lane = (s<<3)|c: s = edge slot (0..7), c = 16B chunk of the 128B half.
// Mask-free loop (padded adjacency). Quarter-wave = 2 edges x 128B = 2
// cache lines (same coalescing as full-row version).
__global__ __launch_bounds__(256) void aggregate_bf16(const uintx4* __restrict__ Xv,
                                                      const int* __restrict__ rowptr,
                                                      const int* __restrict__ degp,
                                                      const int* __restrict__ srt,
                                                      unsigned* __restrict__ out, int n) {
  int b = blockIdx.x;
  int h = b & 1;
  int w = (b >> 1) * 4 + (threadIdx.x >> 6);
  if (w >= n) return;
  int lane = threadIdx.x & 63;
  int c = lane & 7;   // 16B chunk within half-row
  int s = lane >> 3;  // edge slot 0..7

  int p0 = rowptr[w] + s;
  int trips = degp[w] >> 3;
  const uintx4* Xh = Xv + (size_t)h * 8;

  floatx2 acc2[4];
#pragma unroll
  for (int i = 0; i < 4; i++) acc2[i] = floatx2{0.f, 0.f};

#pragma unroll 2
  for (int i = 0; i < trips; i++) {
    int r = srt[p0 + 8 * i];
    uintx4 u = Xh[(size_t)r * 16 + c];
    acc2[0] += bpair(u.x);
    acc2[1] += bpair(u.y);
    acc2[2] += bpair(u.z);
    acc2[3] += bpair(u.w);
  }

  // reduce across slots (lane bits 3,4,5)
#pragma unroll
  for (int i = 0; i < 4; i++) {
#pragma unroll
    for (int k = 0; k < 2; k++) {
      acc2[i][k] += __shfl_xor(acc2[i][k], 8, 64);
      acc2[i][k] += __shfl_xor(acc2[i][k], 16, 64);
      acc2[i][k] += __shfl_xor(acc2[i][k], 32, 64);
    }
  }

  // half-row = 32 dwords; lane (c, s<4) writes dword c*4+s = acc2[s]
  if (s < 4) {
    unsigned pk = (unsigned)f2b(acc2[s][0]) | ((unsigned)f2b(acc2[s][1]) << 16);
    out[(size_t)w * 64 + h * 32 + c * 4 + s] = pk;
  }
}

// ---------- fused MLP: C = (relu(A@Wa^T+ba)) @ Wb^T + bb ----------
__device__ __forceinline__ void stage_wb(char* buf, const uintx4* __restrict__ Wb, int t) {
  for (int idx = t; idx < 2048; idx += 512) {  // idx = 16B-chunk id (8 bf16)
    int nrow = idx >> 4, c = idx & 15;
    uintx4 pk = Wb[idx];
    *(uintx4*)(buf + nrow * 256 + ((c ^ (nrow & 15)) << 4)) = pk;
  }
}

template <int OUT_BF16>
__global__ __launch_bounds__(512) void mlp_kernel(
    const unsigned short* __restrict__ A, const uintx4* __restrict__ Wa16,
    const float* __restrict__ ba, const uintx4* __restrict__ Wb16,
    const float* __restrict__ bb, void* __restrict__ Cout, int n) {
  __shared__ __align__(16) char lds[65536];
  char* bufA = lds;          // Wa, later h
  char* bufB = lds + 32768;  // Wb
  int t = threadIdx.x;
  stage_wb(bufA, Wa16, t);
  stage_wb(bufB, Wb16, t);

  int wave = t >> 6, lane = t & 63;
  int m = lane & 15, q = lane >> 4;
  int rbase = blockIdx.x * 128;
  int rowA = rbase + wave * 16 + m;
  int rA = rowA < n ? rowA : (n - 1);

  bf16x8 af[4];
  const bf16x8* Arow = (const bf16x8*)(A + (size_t)rA * 128);
#pragma unroll
  for (int ks = 0; ks < 4; ks++) af[ks] = Arow[ks * 4 + q];

  __syncthreads();

  floatx4 acc[8];
  floatx4 zf = {0.f, 0.f, 0.f, 0.f};
#pragma unroll
  for (int j = 0; j < 8; j++) acc[j] = zf;
#pragma unroll
  for (int ks = 0; ks < 4; ks++) {
#pragma unroll
    for (int j = 0; j < 8; j++) {
      bf16x8 bf = *(const bf16x8*)(bufA + (j * 16 + m) * 256 + (((ks * 4 + q) ^ m) << 4));
      acc[j] = __builtin_amdgcn_mfma_f32_16x16x32_bf16(af[ks], bf, acc[j], 0, 0, 0);
    }
  }
  __syncthreads();

#pragma unroll
  for (int j = 0; j < 8; j++) {
    float bias = ba[j * 16 + m];
#pragma unroll
    for (int reg = 0; reg < 4; reg++) {
      float v = fmaxf(acc[j][reg] + bias, 0.f);
      int lr = wave * 16 + q * 4 + reg;
      int col = j * 16 + m;
      *(unsigned short*)(bufA + lr * 256 + (((col >> 3) ^ (lr & 15)) << 4) + (col & 7) * 2) =
          f2b(v);
    }
  }
  __syncthreads();

  int lrA = wave * 16 + m;
#pragma unroll
  for (int ks = 0; ks < 4; ks++)
    af[ks] = *(const bf16x8*)(bufA + lrA * 256 + (((ks * 4 + q) ^ m) << 4));
#pragma unroll
  for (int j = 0; j < 8; j++) acc[j] = zf;
#pragma unroll
  for (int ks = 0; ks < 4; ks++) {
#pragma unroll
    for (int j = 0; j < 8; j++) {
      bf16x8 bf = *(const bf16x8*)(bufB + (j * 16 + m) * 256 + (((ks * 4 + q) ^ m) << 4));
      acc[j] = __builtin_amdgcn_mfma_f32_16x16x32_bf16(af[ks], bf, acc[j], 0, 0, 0);
    }
  }

#pragma unroll
  for (int j = 0; j < 8; j++) {
    float bias = bb[j * 16 + m];
#pragma unroll
    for (int reg = 0; reg < 4; reg++) {
      int row = rbase + wave * 16 + q * 4 + reg;
      if (row >= n) continue;
      float v = acc[j][reg] + bias;
      int col = j * 16 + m;
      if (OUT_BF16)
        ((unsigned short*)Cout)[(size_t)row * 128 + col] = f2b(v);
      else
        ((float*)Cout)[(size_t)row * 128 + col] = v;
    }
  }
}

extern "C" void kernel_launch(void* const* d_in, const int* in_sizes, int n_in,
                              void* d_out, int out_size, void* d_ws, size_t ws_size,
                              hipStream_t stream) {
  const float* x   = (const float*)d_in[0];
  const int*   ei  = (const int*)d_in[1];
  const float* w0a = (const float*)d_in[2];
  const float* b0a = (const float*)d_in[3];
  const float* w0b = (const float*)d_in[4];
  const float* b0b = (const float*)d_in[5];
  const float* w1a = (const float*)d_in[6];
  const float* b1a = (const float*)d_in[7];
  const float* w1b = (const float*)d_in[8];
  const float* b1b = (const float*)d_in[9];
  float* out = (float*)d_out;

  int n = in_sizes[0] / 128;  // 100000
  int E = in_sizes[1] / 2;    // 1600000
  const int* src = ei;
  const int* dst = ei + E;
  int nb = (n + 255) / 256;  // 391

  char* w = (char*)d_ws;
  int* rowptr = (int*)w;           w += WS_ALIGN((size_t)(n + 1) * 4);
  int* sbase = (int*)w;            w += WS_ALIGN((size_t)(NBMAX + 1) * 4);
  int* bcnt = (int*)w;             w += WS_ALIGN((size_t)NBMAX * 4);
  int* degp = (int*)w;             w += WS_ALIGN((size_t)n * 4);
  int* srt = (int*)w;              w += WS_ALIGN(((size_t)E + NBMAX * 2048 + 1024) * 4);
  unsigned short* xb = (unsigned short*)w;  w += WS_ALIGN((size_t)(n + 1) * 128 * 2);
  uintx4* wb16 = (uintx4*)w;       w += WS_ALIGN((size_t)8192 * 16);
  // barr (nb*BCAP uints, ~9.6MB) overlaps B1: barr is dead before the first
  // aggregate writes B1.
  unsigned* barr = (unsigned*)w;
  unsigned short* B1 = (unsigned short*)w;

  // ---- CSR build (hierarchical, padded) ----
  hipMemsetAsync(bcnt, 0, (size_t)nb * 4, stream);
  hipMemsetAsync(xb + (size_t)n * 128, 0, 256, stream);  // sentinel zero row
  bucket_split<<<(E + 8191) / 8192, 256, 0, stream>>>(src, dst, bcnt, barr, E, nb);
  bucket_scan<<<1, 512, 0, stream>>>(bcnt, sbase, nb, rowptr, n);
  bucket_csr<<<nb, 256, 0, stream>>>(barr, bcnt, sbase, rowptr, degp, srt, n);

  // ---- weights -> bf16 (once) ----
  wcvt_kernel<<<32, 256, 0, stream>>>(w0a, w0b, w1a, w1b, wb16);

  // ---- x -> bf16 ----
  cvt_kernel<<<(n * 32 + 255) / 256, 256, 0, stream>>>(x, xb, n * 32);

  int agg_grid = ((n + 3) / 4) * 2;  // node-groups x 2 halves
  int mlp_grid = (n + 127) / 128;

  // ---- layer 1 ----  (xb -> B1 -> xb)
  aggregate_bf16<<<agg_grid, 256, 0, stream>>>((const uintx4*)xb, rowptr, degp, srt,
                                               (unsigned*)B1, n);
  mlp_kernel<1><<<mlp_grid, 512, 0, stream>>>(B1, wb16, b0a, wb16 + 2048, b0b, xb, n);

  // ---- layer 2 ----  (xb -> B1 -> out)
  aggregate_bf16<<<agg_grid, 256, 0, stream>>>((const uintx4*)xb, rowptr, degp, srt,
                                               (unsigned*)B1, n);
  mlp_kernel<0><<<mlp_grid, 512, 0, stream>>>(B1, wb16 + 4096, b1a, wb16 + 6144, b1b, out, n);
}

// Round 7
// 319.951 us; speedup vs baseline: 1.1571x; 1.1571x over previous
//
#include <hip/hip_runtime.h>

// GIN 2-layer, N=100000, E=1600000, D=128.
// R12: dispatch-count consolidation. Aggregate/scan/csr reverted to R7
// (best measured: 59.6us; R9/R10/R11 slicing+padding experiments all
// regressed or tied -> gather stream is at its structural floor). Theory:
// ~120us of the 331 is launch overhead (9-11 graph nodes x ~10us).
// Graph shrunk 9 -> 7 nodes: prep_kernel fuses {cvt, weight->bf16, bcnt
// zero}; bucket_scan merged into bucket_csr (per-block prefix reduce).

typedef __attribute__((ext_vector_type(8))) short bf16x8;
typedef __attribute__((ext_vector_type(4))) float floatx4;
typedef __attribute__((ext_vector_type(2))) float floatx2;
typedef __attribute__((ext_vector_type(4))) unsigned uintx4;

#define WS_ALIGN(x) (((x) + 255) & ~(size_t)255)
#define NBMAX 400   // max buckets (n <= 102400)
#define BCAP 6144   // per-bucket capacity (mean 4096, sd ~64)

__device__ __forceinline__ unsigned short f2b(float f) {  // RTNE fp32->bf16
  unsigned u = __builtin_bit_cast(unsigned, f);
  u = (u + 0x7FFF + ((u >> 16) & 1)) >> 16;
  return (unsigned short)u;
}

// unpack a dword of 2 bf16 into {lo,hi} as f32 pair
__device__ __forceinline__ floatx2 bpair(unsigned d) {
  floatx2 r;
  r[0] = __builtin_bit_cast(float, d << 16);
  r[1] = __builtin_bit_cast(float, d & 0xffff0000u);
  return r;
}

// ---------- prep: x->bf16, weights->bf16, bcnt zero (one dispatch) ----------
__global__ __launch_bounds__(256) void prep_kernel(const float* __restrict__ x,
                                                   unsigned short* __restrict__ xb,
                                                   const float* __restrict__ w0a,
                                                   const float* __restrict__ w0b,
                                                   const float* __restrict__ w1a,
                                                   const float* __restrict__ w1b,
                                                   uintx4* __restrict__ wb16,
                                                   int* __restrict__ bcnt, int n4) {
  int i = blockIdx.x * 256 + threadIdx.x;
  if (i < n4) {  // x fp32 -> xb bf16 (row-major), 1 float4 per thread
    float4 v = ((const float4*)x)[i];
    uint2 pk;
    pk.x = (unsigned)f2b(v.x) | ((unsigned)f2b(v.y) << 16);
    pk.y = (unsigned)f2b(v.z) | ((unsigned)f2b(v.w) << 16);
    ((uint2*)xb)[i] = pk;
  }
  if (i < 8192) {  // 4 weight matrices 128x128 -> bf16 chunks
    const float* W = (i < 2048) ? w0a : (i < 4096) ? w0b : (i < 6144) ? w1a : w1b;
    int j = i & 2047;
    float4 a = ((const float4*)W)[j * 2];
    float4 b = ((const float4*)W)[j * 2 + 1];
    uintx4 pk;
    pk.x = (unsigned)f2b(a.x) | ((unsigned)f2b(a.y) << 16);
    pk.y = (unsigned)f2b(a.z) | ((unsigned)f2b(a.w) << 16);
    pk.z = (unsigned)f2b(b.x) | ((unsigned)f2b(b.y) << 16);
    pk.w = (unsigned)f2b(b.z) | ((unsigned)f2b(b.w) << 16);
    wb16[i] = pk;
  }
  if (i < NBMAX) bcnt[i] = 0;
}

// ---------- phase A: multisplit edges into 256-node buckets ----------
__global__ __launch_bounds__(256) void bucket_split(const int* __restrict__ src,
                                                    const int* __restrict__ dst,
                                                    int* __restrict__ bcnt,
                                                    unsigned* __restrict__ barr, int E, int nb) {
  __shared__ int cnt[NBMAX], base[NBMAX], cur[NBMAX];
  int t = threadIdx.x;
  for (int i = t; i < nb; i += 256) { cnt[i] = 0; cur[i] = 0; }
  __syncthreads();
  int e0 = blockIdx.x * 8192;
  int s[32], d[32];
#pragma unroll
  for (int k = 0; k < 32; k++) {
    int e = e0 + k * 256 + t;
    if (e < E) { s[k] = src[e]; d[k] = dst[e]; } else { d[k] = -1; }
  }
#pragma unroll
  for (int k = 0; k < 32; k++)
    if (d[k] >= 0) atomicAdd(&cnt[d[k] >> 8], 1);
  __syncthreads();
  for (int i = t; i < nb; i += 256) base[i] = cnt[i] ? atomicAdd(&bcnt[i], cnt[i]) : 0;
  __syncthreads();
#pragma unroll
  for (int k = 0; k < 32; k++)
    if (d[k] >= 0) {
      int b = d[k] >> 8;
      int r = atomicAdd(&cur[b], 1);
      barr[(size_t)b * BCAP + base[b] + r] = ((unsigned)(d[k] & 255) << 17) | (unsigned)s[k];
    }
}

// ---------- phase B+C merged: per-bucket CSR finalize with inline prefix ----------
// Each block computes its own sbase = sum(bcnt[0..b)) via strided partial +
// LDS tree reduce (replaces the bucket_scan dispatch).
__global__ __launch_bounds__(256) void bucket_csr(const unsigned* __restrict__ barr,
                                                  const int* __restrict__ bcnt,
                                                  int* __restrict__ rowptr, int* __restrict__ srt,
                                                  int n, int nb) {
  __shared__ int cnt[256], off[256], off2[256], red[256];
  int b = blockIdx.x, t = threadIdx.x;
  int cb = bcnt[b];
  int node0 = b * 256;
  int nlocal = min(256, n - node0);
  cnt[t] = 0;
  off2[t] = 0;
  // inline exclusive prefix over buckets [0, b)
  int partial = 0;
  for (int i = t; i < b; i += 256) partial += bcnt[i];
  red[t] = partial;
  __syncthreads();
  for (int o = 128; o > 0; o >>= 1) {
    if (t < o) red[t] += red[t + o];
    __syncthreads();
  }
  int sb = red[0];

  const unsigned* bp = barr + (size_t)b * BCAP;
  for (int i = t; i < cb; i += 256) atomicAdd(&cnt[bp[i] >> 17], 1);
  __syncthreads();
  int v = cnt[t];
  off[t] = v;
  __syncthreads();
  for (int o = 1; o < 256; o <<= 1) {
    int add = (t >= o) ? off[t - o] : 0;
    __syncthreads();
    off[t] += add;
    __syncthreads();
  }
  int excl = off[t] - v;
  if (t < nlocal) rowptr[node0 + t] = sb + excl;
  cnt[t] = excl;
  __syncthreads();
  for (int i = t; i < cb; i += 256) {
    unsigned pk = bp[i];
    int local = pk >> 17;
    int r = atomicAdd(&off2[local], 1);
    srt[sb + cnt[local] + r] = pk & 0x1FFFF;
  }
  if (b == nb - 1 && t == 0) rowptr[n] = sb + cb;
}

// ---------- aggregation (bf16 in/out, fp32 accumulate) ----------
// one wave per node. lane = (s<<4)|c: s = edge slot (0..3), c = 16B chunk
// (0..15). Trips processed in groups of 4: 4 srt broadcast loads issued
// back-to-back (one vmcnt batch), then 4 independent 1KB gathers, then
// accumulate. One latency round trip covers 16 edges (mean degree 16).
__global__ __launch_bounds__(256) void aggregate_bf16(const unsigned short* __restrict__ X,
                                                      const int* __restrict__ rowptr,
                                                      const int* __restrict__ srt,
                                                      unsigned short* __restrict__ out, int n) {
  int w = blockIdx.x * 4 + (threadIdx.x >> 6);
  if (w >= n) return;
  int lane = threadIdx.x & 63;
  int c = lane & 15;  // 16B chunk within row
  int s = lane >> 4;  // edge slot
  const uintx4* Xv = (const uintx4*)X;  // 16 uintx4 per row

  int p0 = rowptr[w], e = rowptr[w + 1];
  int deg = e - p0;
  int trips = (deg + 3) >> 2;

  // self row: issue early (slot 0 lanes only); accumulated after the loop
  uintx4 uself = {0, 0, 0, 0};
  if (s == 0) uself = Xv[(size_t)w * 16 + c];

  floatx2 acc2[4];
#pragma unroll
  for (int i = 0; i < 4; i++) acc2[i] = floatx2{0.f, 0.f};

  for (int g = 0; g < trips; g += 4) {
    int idx[4];
    bool val[4];
#pragma unroll
    for (int k = 0; k < 4; k++) {
      int j = (g + k) * 4 + s;
      val[k] = j < deg;
      idx[k] = srt[p0 + (val[k] ? j : 0)];
    }
    uintx4 u[4];
#pragma unroll
    for (int k = 0; k < 4; k++) u[k] = Xv[(size_t)idx[k] * 16 + c];
#pragma unroll
    for (int k = 0; k < 4; k++) {
      if (!val[k]) u[k] = uintx4{0, 0, 0, 0};
      acc2[0] += bpair(u[k].x);
      acc2[1] += bpair(u[k].y);
      acc2[2] += bpair(u[k].z);
      acc2[3] += bpair(u[k].w);
    }
  }

  // fold in self row (zeros for s != 0 lanes)
  acc2[0] += bpair(uself.x);
  acc2[1] += bpair(uself.y);
  acc2[2] += bpair(uself.z);
  acc2[3] += bpair(uself.w);

  // reduce across slots (lane bits 4,5)
#pragma unroll
  for (int i = 0; i < 4; i++) {
#pragma unroll
    for (int k = 0; k < 2; k++) {
      acc2[i][k] += __shfl_xor(acc2[i][k], 16, 64);
      acc2[i][k] += __shfl_xor(acc2[i][k], 32, 64);
    }
  }

  // lane (c,s) writes dword c*4+s = cols (c*8+2s, c*8+2s+1) = acc2[s]
  unsigned pk = (unsigned)f2b(acc2[s][0]) | ((unsigned)f2b(acc2[s][1]) << 16);
  ((unsigned*)out)[(size_t)w * 64 + c * 4 + s] = pk;
}

// ---------- fused MLP: C = (relu(A@Wa^T+ba)) @ Wb^T + bb ----------
__device__ __forceinline__ void stage_wb(char* buf, const uintx4* __restrict__ Wb, int t) {
  for (int idx = t; idx < 2048; idx += 512) {  // idx = 16B-chunk id (8 bf16)
    int nrow = idx >> 4, c = idx & 15;
    uintx4 pk = Wb[idx];
    *(uintx4*)(buf + nrow * 256 + ((c ^ (nrow & 15)) << 4)) = pk;
  }
}

template <int OUT_BF16>
__global__ __launch_bounds__(512) void mlp_kernel(
    const unsigned short* __restrict__ A, const uintx4* __restrict__ Wa16,
    const float* __restrict__ ba, const uintx4* __restrict__ Wb16,
    const float* __restrict__ bb, void* __restrict__ Cout, int n) {
  __shared__ __align__(16) char lds[65536];
  char* bufA = lds;          // Wa, later h
  char* bufB = lds + 32768;  // Wb
  int t = threadIdx.x;
  stage_wb(bufA, Wa16, t);
  stage_wb(bufB, Wb16, t);

  int wave = t >> 6, lane = t & 63;
  int m = lane & 15, q = lane >> 4;
  int rbase = blockIdx.x * 128;
  int rowA = rbase + wave * 16 + m;
  int rA = rowA < n ? rowA : (n - 1);

  bf16x8 af[4];
  const bf16x8* Arow = (const bf16x8*)(A + (size_t)rA * 128);
#pragma unroll
  for (int ks = 0; ks < 4; ks++) af[ks] = Arow[ks * 4 + q];

  __syncthreads();

  floatx4 acc[8];
  floatx4 zf = {0.f, 0.f, 0.f, 0.f};
#pragma unroll
  for (int j = 0; j < 8; j++) acc[j] = zf;
#pragma unroll
  for (int ks = 0; ks < 4; ks++) {
#pragma unroll
    for (int j = 0; j < 8; j++) {
      bf16x8 bf = *(const bf16x8*)(bufA + (j * 16 + m) * 256 + (((ks * 4 + q) ^ m) << 4));
      acc[j] = __builtin_amdgcn_mfma_f32_16x16x32_bf16(af[ks], bf, acc[j], 0, 0, 0);
    }
  }
  __syncthreads();

#pragma unroll
  for (int j = 0; j < 8; j++) {
    float bias = ba[j * 16 + m];
#pragma unroll
    for (int reg = 0; reg < 4; reg++) {
      float v = fmaxf(acc[j][reg] + bias, 0.f);
      int lr = wave * 16 + q * 4 + reg;
      int col = j * 16 + m;
      *(unsigned short*)(bufA + lr * 256 + (((col >> 3) ^ (lr & 15)) << 4) + (col & 7) * 2) =
          f2b(v);
    }
  }
  __syncthreads();

  int lrA = wave * 16 + m;
#pragma unroll
  for (int ks = 0; ks < 4; ks++)
    af[ks] = *(const bf16x8*)(bufA + lrA * 256 + (((ks * 4 + q) ^ m) << 4));
#pragma unroll
  for (int j = 0; j < 8; j++) acc[j] = zf;
#pragma unroll
  for (int ks = 0; ks < 4; ks++) {
#pragma unroll
    for (int j = 0; j < 8; j++) {
      bf16x8 bf = *(const bf16x8*)(bufB + (j * 16 + m) * 256 + (((ks * 4 + q) ^ m) << 4));
      acc[j] = __builtin_amdgcn_mfma_f32_16x16x32_bf16(af[ks], bf, acc[j], 0, 0, 0);
    }
  }

#pragma unroll
  for (int j = 0; j < 8; j++) {
    float bias = bb[j * 16 + m];
#pragma unroll
    for (int reg = 0; reg < 4; reg++) {
      int row = rbase + wave * 16 + q * 4 + reg;
      if (row >= n) continue;
      float v = acc[j][reg] + bias;
      int col = j * 16 + m;
      if (OUT_BF16)
        ((unsigned short*)Cout)[(size_t)row * 128 + col] = f2b(v);
      else
        ((float*)Cout)[(size_t)row * 128 + col] = v;
    }
  }
}

extern "C" void kernel_launch(void* const* d_in, const int* in_sizes, int n_in,
                              void* d_out, int out_size, void* d_ws, size_t ws_size,
                              hipStream_t stream) {
  const float* x   = (const float*)d_in[0];
  const int*   ei  = (const int*)d_in[1];
  const float* w0a = (const float*)d_in[2];
  const float* b0a = (const float*)d_in[3];
  const float* w0b = (const float*)d_in[4];
  const float* b0b = (const float*)d_in[5];
  const float* w1a = (const float*)d_in[6];
  const float* b1a = (const float*)d_in[7];
  const float* w1b = (const float*)d_in[8];
  const float* b1b = (const float*)d_in[9];
  float* out = (float*)d_out;

  int n = in_sizes[0] / 128;  // 100000
  int E = in_sizes[1] / 2;    // 1600000
  const int* src = ei;
  const int* dst = ei + E;
  int nb = (n + 255) / 256;  // 391

  char* w = (char*)d_ws;
  int* rowptr = (int*)w;           w += WS_ALIGN((size_t)(n + 1) * 4);
  int* bcnt = (int*)w;             w += WS_ALIGN((size_t)NBMAX * 4);
  int* srt = (int*)w;              w += WS_ALIGN((size_t)E * 4);
  unsigned short* xb = (unsigned short*)w;  w += WS_ALIGN((size_t)n * 128 * 2);
  uintx4* wb16 = (uintx4*)w;       w += WS_ALIGN((size_t)8192 * 16);
  // barr (nb*BCAP uints, ~9.6MB) overlaps B1: barr is dead before the first
  // aggregate writes B1.
  unsigned* barr = (unsigned*)w;
  unsigned short* B1 = (unsigned short*)w;

  int n4 = n * 32;

  // ---- prep (cvt + wcvt + bcnt zero, one dispatch) ----
  prep_kernel<<<(n4 + 255) / 256, 256, 0, stream>>>(x, xb, w0a, w0b, w1a, w1b, wb16, bcnt, n4);

  // ---- CSR build (2 dispatches) ----
  bucket_split<<<(E + 8191) / 8192, 256, 0, stream>>>(src, dst, bcnt, barr, E, nb);
  bucket_csr<<<nb, 256, 0, stream>>>(barr, bcnt, rowptr, srt, n, nb);

  int agg_grid = (n + 3) / 4;
  int mlp_grid = (n + 127) / 128;

  // ---- layer 1 ----  (xb -> B1 -> xb)
  aggregate_bf16<<<agg_grid, 256, 0, stream>>>(xb, rowptr, srt, (unsigned short*)B1, n);
  mlp_kernel<1><<<mlp_grid, 512, 0, stream>>>(B1, wb16, b0a, wb16 + 2048, b0b, xb, n);

  // ---- layer 2 ----  (xb -> B1 -> out)
  aggregate_bf16<<<agg_grid, 256, 0, stream>>>(xb, rowptr, srt, (unsigned short*)B1, n);
  mlp_kernel<0><<<mlp_grid, 512, 0, stream>>>(B1, wb16 + 4096, b1a, wb16 + 6144, b1b, out, n);
}

// Round 8
// 304.864 us; speedup vs baseline: 1.2144x; 1.0495x over previous
//
#include <hip/hip_runtime.h>

// GIN 2-layer, N=100000, E=1600000, D=128.
// R13 = R12 graph (7 nodes) + non-agg kernel diet:
//  - mlp epilogue: stage C in LDS row-major, then coalesced uintx4 global
//    stores (was per-element 2B/4B scatter, ~16 lines per store instr).
//  - bucket_split: int4-vectorized edge loads (full blocks), scalar tail.
//  - bucket_csr: uint4-vectorized barr reads in both passes.
// Aggregate untouched (59.8us floor = L1 miss-queue saturation: lines x
// latency / MSHR; insensitive to VALU/FETCH/ILP per R7-R11).

typedef __attribute__((ext_vector_type(8))) short bf16x8;
typedef __attribute__((ext_vector_type(4))) float floatx4;
typedef __attribute__((ext_vector_type(2))) float floatx2;
typedef __attribute__((ext_vector_type(4))) unsigned uintx4;

#define WS_ALIGN(x) (((x) + 255) & ~(size_t)255)
#define NBMAX 400   // max buckets (n <= 102400)
#define BCAP 6144   // per-bucket capacity (mean 4096, sd ~64)

__device__ __forceinline__ unsigned short f2b(float f) {  // RTNE fp32->bf16
  unsigned u = __builtin_bit_cast(unsigned, f);
  u = (u + 0x7FFF + ((u >> 16) & 1)) >> 16;
  return (unsigned short)u;
}

// unpack a dword of 2 bf16 into {lo,hi} as f32 pair
__device__ __forceinline__ floatx2 bpair(unsigned d) {
  floatx2 r;
  r[0] = __builtin_bit_cast(float, d << 16);
  r[1] = __builtin_bit_cast(float, d & 0xffff0000u);
  return r;
}

// ---------- prep: x->bf16, weights->bf16, bcnt zero (one dispatch) ----------
__global__ __launch_bounds__(256) void prep_kernel(const float* __restrict__ x,
                                                   unsigned short* __restrict__ xb,
                                                   const float* __restrict__ w0a,
                                                   const float* __restrict__ w0b,
                                                   const float* __restrict__ w1a,
                                                   const float* __restrict__ w1b,
                                                   uintx4* __restrict__ wb16,
                                                   int* __restrict__ bcnt, int n4) {
  int i = blockIdx.x * 256 + threadIdx.x;
  if (i < n4) {  // x fp32 -> xb bf16 (row-major), 1 float4 per thread
    float4 v = ((const float4*)x)[i];
    uint2 pk;
    pk.x = (unsigned)f2b(v.x) | ((unsigned)f2b(v.y) << 16);
    pk.y = (unsigned)f2b(v.z) | ((unsigned)f2b(v.w) << 16);
    ((uint2*)xb)[i] = pk;
  }
  if (i < 8192) {  // 4 weight matrices 128x128 -> bf16 chunks
    const float* W = (i < 2048) ? w0a : (i < 4096) ? w0b : (i < 6144) ? w1a : w1b;
    int j = i & 2047;
    float4 a = ((const float4*)W)[j * 2];
    float4 b = ((const float4*)W)[j * 2 + 1];
    uintx4 pk;
    pk.x = (unsigned)f2b(a.x) | ((unsigned)f2b(a.y) << 16);
    pk.y = (unsigned)f2b(a.z) | ((unsigned)f2b(a.w) << 16);
    pk.z = (unsigned)f2b(b.x) | ((unsigned)f2b(b.y) << 16);
    pk.w = (unsigned)f2b(b.z) | ((unsigned)f2b(b.w) << 16);
    wb16[i] = pk;
  }
  if (i < NBMAX) bcnt[i] = 0;
}

// ---------- phase A: multisplit edges into 256-node buckets ----------
__global__ __launch_bounds__(256) void bucket_split(const int* __restrict__ src,
                                                    const int* __restrict__ dst,
                                                    int* __restrict__ bcnt,
                                                    unsigned* __restrict__ barr, int E, int nb) {
  __shared__ int cnt[NBMAX], base[NBMAX], cur[NBMAX];
  int t = threadIdx.x;
  for (int i = t; i < nb; i += 256) { cnt[i] = 0; cur[i] = 0; }
  __syncthreads();
  int e0 = blockIdx.x * 8192;
  int s[32], d[32];
  if (e0 + 8192 <= E) {  // full block: int4 vector loads (E % 4 == 0 req'd? only within full range)
    const int4* src4 = (const int4*)src;
    const int4* dst4 = (const int4*)dst;
    int b4 = blockIdx.x * 2048;
#pragma unroll
    for (int k = 0; k < 8; k++) {
      int4 sv = src4[b4 + k * 256 + t];
      int4 dv = dst4[b4 + k * 256 + t];
      s[k * 4 + 0] = sv.x; d[k * 4 + 0] = dv.x;
      s[k * 4 + 1] = sv.y; d[k * 4 + 1] = dv.y;
      s[k * 4 + 2] = sv.z; d[k * 4 + 2] = dv.z;
      s[k * 4 + 3] = sv.w; d[k * 4 + 3] = dv.w;
    }
  } else {  // tail block: scalar with guard
#pragma unroll
    for (int k = 0; k < 32; k++) {
      int e = e0 + k * 256 + t;
      if (e < E) { s[k] = src[e]; d[k] = dst[e]; } else { d[k] = -1; }
    }
  }
#pragma unroll
  for (int k = 0; k < 32; k++)
    if (d[k] >= 0) atomicAdd(&cnt[d[k] >> 8], 1);
  __syncthreads();
  for (int i = t; i < nb; i += 256) base[i] = cnt[i] ? atomicAdd(&bcnt[i], cnt[i]) : 0;
  __syncthreads();
#pragma unroll
  for (int k = 0; k < 32; k++)
    if (d[k] >= 0) {
      int b = d[k] >> 8;
      int r = atomicAdd(&cur[b], 1);
      barr[(size_t)b * BCAP + base[b] + r] = ((unsigned)(d[k] & 255) << 17) | (unsigned)s[k];
    }
}

// ---------- phase B+C merged: per-bucket CSR finalize with inline prefix ----------
__global__ __launch_bounds__(256) void bucket_csr(const unsigned* __restrict__ barr,
                                                  const int* __restrict__ bcnt,
                                                  int* __restrict__ rowptr, int* __restrict__ srt,
                                                  int n, int nb) {
  __shared__ int cnt[256], off[256], off2[256], red[256];
  int b = blockIdx.x, t = threadIdx.x;
  int cb = bcnt[b];
  int node0 = b * 256;
  int nlocal = min(256, n - node0);
  cnt[t] = 0;
  off2[t] = 0;
  // inline exclusive prefix over buckets [0, b)
  int partial = 0;
  for (int i = t; i < b; i += 256) partial += bcnt[i];
  red[t] = partial;
  __syncthreads();
  for (int o = 128; o > 0; o >>= 1) {
    if (t < o) red[t] += red[t + o];
    __syncthreads();
  }
  int sb = red[0];

  const unsigned* bp = barr + (size_t)b * BCAP;
  const uint4* bp4 = (const uint4*)bp;
  int cb4 = cb >> 2;
  for (int i = t; i < cb4; i += 256) {
    uint4 v4 = bp4[i];
    atomicAdd(&cnt[v4.x >> 17], 1);
    atomicAdd(&cnt[v4.y >> 17], 1);
    atomicAdd(&cnt[v4.z >> 17], 1);
    atomicAdd(&cnt[v4.w >> 17], 1);
  }
  for (int i = cb4 * 4 + t; i < cb; i += 256) atomicAdd(&cnt[bp[i] >> 17], 1);
  __syncthreads();
  int v = cnt[t];
  off[t] = v;
  __syncthreads();
  for (int o = 1; o < 256; o <<= 1) {
    int add = (t >= o) ? off[t - o] : 0;
    __syncthreads();
    off[t] += add;
    __syncthreads();
  }
  int excl = off[t] - v;
  if (t < nlocal) rowptr[node0 + t] = sb + excl;
  cnt[t] = excl;
  __syncthreads();
  for (int i = t; i < cb4; i += 256) {
    uint4 v4 = bp4[i];
    unsigned pks[4] = {v4.x, v4.y, v4.z, v4.w};
#pragma unroll
    for (int j = 0; j < 4; j++) {
      int local = pks[j] >> 17;
      int r = atomicAdd(&off2[local], 1);
      srt[sb + cnt[local] + r] = pks[j] & 0x1FFFF;
    }
  }
  for (int i = cb4 * 4 + t; i < cb; i += 256) {
    unsigned pk = bp[i];
    int local = pk >> 17;
    int r = atomicAdd(&off2[local], 1);
    srt[sb + cnt[local] + r] = pk & 0x1FFFF;
  }
  if (b == nb - 1 && t == 0) rowptr[n] = sb + cb;
}

// ---------- aggregation (bf16 in/out, fp32 accumulate) ----------
// UNCHANGED from R12 (measured floor).
__global__ __launch_bounds__(256) void aggregate_bf16(const unsigned short* __restrict__ X,
                                                      const int* __restrict__ rowptr,
                                                      const int* __restrict__ srt,
                                                      unsigned short* __restrict__ out, int n) {
  int w = blockIdx.x * 4 + (threadIdx.x >> 6);
  if (w >= n) return;
  int lane = threadIdx.x & 63;
  int c = lane & 15;  // 16B chunk within row
  int s = lane >> 4;  // edge slot
  const uintx4* Xv = (const uintx4*)X;  // 16 uintx4 per row

  int p0 = rowptr[w], e = rowptr[w + 1];
  int deg = e - p0;
  int trips = (deg + 3) >> 2;

  // self row: issue early (slot 0 lanes only); accumulated after the loop
  uintx4 uself = {0, 0, 0, 0};
  if (s == 0) uself = Xv[(size_t)w * 16 + c];

  floatx2 acc2[4];
#pragma unroll
  for (int i = 0; i < 4; i++) acc2[i] = floatx2{0.f, 0.f};

  for (int g = 0; g < trips; g += 4) {
    int idx[4];
    bool val[4];
#pragma unroll
    for (int k = 0; k < 4; k++) {
      int j = (g + k) * 4 + s;
      val[k] = j < deg;
      idx[k] = srt[p0 + (val[k] ? j : 0)];
    }
    uintx4 u[4];
#pragma unroll
    for (int k = 0; k < 4; k++) u[k] = Xv[(size_t)idx[k] * 16 + c];
#pragma unroll
    for (int k = 0; k < 4; k++) {
      if (!val[k]) u[k] = uintx4{0, 0, 0, 0};
      acc2[0] += bpair(u[k].x);
      acc2[1] += bpair(u[k].y);
      acc2[2] += bpair(u[k].z);
      acc2[3] += bpair(u[k].w);
    }
  }

  // fold in self row (zeros for s != 0 lanes)
  acc2[0] += bpair(uself.x);
  acc2[1] += bpair(uself.y);
  acc2[2] += bpair(uself.z);
  acc2[3] += bpair(uself.w);

  // reduce across slots (lane bits 4,5)
#pragma unroll
  for (int i = 0; i < 4; i++) {
#pragma unroll
    for (int k = 0; k < 2; k++) {
      acc2[i][k] += __shfl_xor(acc2[i][k], 16, 64);
      acc2[i][k] += __shfl_xor(acc2[i][k], 32, 64);
    }
  }

  // lane (c,s) writes dword c*4+s = cols (c*8+2s, c*8+2s+1) = acc2[s]
  unsigned pk = (unsigned)f2b(acc2[s][0]) | ((unsigned)f2b(acc2[s][1]) << 16);
  ((unsigned*)out)[(size_t)w * 64 + c * 4 + s] = pk;
}

// ---------- fused MLP: C = (relu(A@Wa^T+ba)) @ Wb^T + bb ----------
__device__ __forceinline__ void stage_wb(char* buf, const uintx4* __restrict__ Wb, int t) {
  for (int idx = t; idx < 2048; idx += 512) {  // idx = 16B-chunk id (8 bf16)
    int nrow = idx >> 4, c = idx & 15;
    uintx4 pk = Wb[idx];
    *(uintx4*)(buf + nrow * 256 + ((c ^ (nrow & 15)) << 4)) = pk;
  }
}

template <int OUT_BF16>
__global__ __launch_bounds__(512) void mlp_kernel(
    const unsigned short* __restrict__ A, const uintx4* __restrict__ Wa16,
    const float* __restrict__ ba, const uintx4* __restrict__ Wb16,
    const float* __restrict__ bb, void* __restrict__ Cout, int n) {
  __shared__ __align__(16) char lds[65536];
  char* bufA = lds;          // Wa, later h, later C-staging
  char* bufB = lds + 32768;  // Wb
  int t = threadIdx.x;
  stage_wb(bufA, Wa16, t);
  stage_wb(bufB, Wb16, t);

  int wave = t >> 6, lane = t & 63;
  int m = lane & 15, q = lane >> 4;
  int rbase = blockIdx.x * 128;
  int rowA = rbase + wave * 16 + m;
  int rA = rowA < n ? rowA : (n - 1);

  bf16x8 af[4];
  const bf16x8* Arow = (const bf16x8*)(A + (size_t)rA * 128);
#pragma unroll
  for (int ks = 0; ks < 4; ks++) af[ks] = Arow[ks * 4 + q];

  __syncthreads();

  floatx4 acc[8];
  floatx4 zf = {0.f, 0.f, 0.f, 0.f};
#pragma unroll
  for (int j = 0; j < 8; j++) acc[j] = zf;
#pragma unroll
  for (int ks = 0; ks < 4; ks++) {
#pragma unroll
    for (int j = 0; j < 8; j++) {
      bf16x8 bf = *(const bf16x8*)(bufA + (j * 16 + m) * 256 + (((ks * 4 + q) ^ m) << 4));
      acc[j] = __builtin_amdgcn_mfma_f32_16x16x32_bf16(af[ks], bf, acc[j], 0, 0, 0);
    }
  }
  __syncthreads();

#pragma unroll
  for (int j = 0; j < 8; j++) {
    float bias = ba[j * 16 + m];
#pragma unroll
    for (int reg = 0; reg < 4; reg++) {
      float v = fmaxf(acc[j][reg] + bias, 0.f);
      int lr = wave * 16 + q * 4 + reg;
      int col = j * 16 + m;
      *(unsigned short*)(bufA + lr * 256 + (((col >> 3) ^ (lr & 15)) << 4) + (col & 7) * 2) =
          f2b(v);
    }
  }
  __syncthreads();

  int lrA = wave * 16 + m;
#pragma unroll
  for (int ks = 0; ks < 4; ks++)
    af[ks] = *(const bf16x8*)(bufA + lrA * 256 + (((ks * 4 + q) ^ m) << 4));
#pragma unroll
  for (int j = 0; j < 8; j++) acc[j] = zf;
#pragma unroll
  for (int ks = 0; ks < 4; ks++) {
#pragma unroll
    for (int j = 0; j < 8; j++) {
      bf16x8 bf = *(const bf16x8*)(bufB + (j * 16 + m) * 256 + (((ks * 4 + q) ^ m) << 4));
      acc[j] = __builtin_amdgcn_mfma_f32_16x16x32_bf16(af[ks], bf, acc[j], 0, 0, 0);
    }
  }

  // ---- coalesced epilogue: stage C in LDS row-major, then uintx4 stores ----
  __syncthreads();  // all LDS reads (bufA af-loads, bufB MFMA) complete
  int nrows = min(128, n - rbase);
  if (OUT_BF16) {
    // bf16 rows of 256B at bufA (32KB)
#pragma unroll
    for (int j = 0; j < 8; j++) {
      float bias = bb[j * 16 + m];
#pragma unroll
      for (int reg = 0; reg < 4; reg++) {
        int lr = wave * 16 + q * 4 + reg;
        int col = j * 16 + m;
        *(unsigned short*)(bufA + lr * 256 + col * 2) = f2b(acc[j][reg] + bias);
      }
    }
    __syncthreads();
    const uintx4* sv = (const uintx4*)bufA;
    uintx4* gout = (uintx4*)((unsigned short*)Cout + (size_t)rbase * 128);
    int chunks = nrows * 16;  // 16 x 16B per row
    for (int i = t; i < chunks; i += 512) gout[i] = sv[i];
  } else {
    // fp32 rows of 512B across full 64KB LDS
    float* stg = (float*)lds;
#pragma unroll
    for (int j = 0; j < 8; j++) {
      float bias = bb[j * 16 + m];
#pragma unroll
      for (int reg = 0; reg < 4; reg++) {
        int lr = wave * 16 + q * 4 + reg;
        int col = j * 16 + m;
        stg[lr * 128 + col] = acc[j][reg] + bias;
      }
    }
    __syncthreads();
    const uintx4* sv = (const uintx4*)lds;
    uintx4* gout = (uintx4*)((float*)Cout + (size_t)rbase * 128);
    int chunks = nrows * 32;  // 32 x 16B per row
    for (int i = t; i < chunks; i += 512) gout[i] = sv[i];
  }
}

extern "C" void kernel_launch(void* const* d_in, const int* in_sizes, int n_in,
                              void* d_out, int out_size, void* d_ws, size_t ws_size,
                              hipStream_t stream) {
  const float* x   = (const float*)d_in[0];
  const int*   ei  = (const int*)d_in[1];
  const float* w0a = (const float*)d_in[2];
  const float* b0a = (const float*)d_in[3];
  const float* w0b = (const float*)d_in[4];
  const float* b0b = (const float*)d_in[5];
  const float* w1a = (const float*)d_in[6];
  const float* b1a = (const float*)d_in[7];
  const float* w1b = (const float*)d_in[8];
  const float* b1b = (const float*)d_in[9];
  float* out = (float*)d_out;

  int n = in_sizes[0] / 128;  // 100000
  int E = in_sizes[1] / 2;    // 1600000
  const int* src = ei;
  const int* dst = ei + E;
  int nb = (n + 255) / 256;  // 391

  char* w = (char*)d_ws;
  int* rowptr = (int*)w;           w += WS_ALIGN((size_t)(n + 1) * 4);
  int* bcnt = (int*)w;             w += WS_ALIGN((size_t)NBMAX * 4);
  int* srt = (int*)w;              w += WS_ALIGN((size_t)E * 4);
  unsigned short* xb = (unsigned short*)w;  w += WS_ALIGN((size_t)n * 128 * 2);
  uintx4* wb16 = (uintx4*)w;       w += WS_ALIGN((size_t)8192 * 16);
  // barr (nb*BCAP uints, ~9.6MB) overlaps B1: barr is dead before the first
  // aggregate writes B1.
  unsigned* barr = (unsigned*)w;
  unsigned short* B1 = (unsigned short*)w;

  int n4 = n * 32;

  // ---- prep (cvt + wcvt + bcnt zero, one dispatch) ----
  prep_kernel<<<(n4 + 255) / 256, 256, 0, stream>>>(x, xb, w0a, w0b, w1a, w1b, wb16, bcnt, n4);

  // ---- CSR build (2 dispatches) ----
  bucket_split<<<(E + 8191) / 8192, 256, 0, stream>>>(src, dst, bcnt, barr, E, nb);
  bucket_csr<<<nb, 256, 0, stream>>>(barr, bcnt, rowptr, srt, n, nb);

  int agg_grid = (n + 3) / 4;
  int mlp_grid = (n + 127) / 128;

  // ---- layer 1 ----  (xb -> B1 -> xb)
  aggregate_bf16<<<agg_grid, 256, 0, stream>>>(xb, rowptr, srt, (unsigned short*)B1, n);
  mlp_kernel<1><<<mlp_grid, 512, 0, stream>>>(B1, wb16, b0a, wb16 + 2048, b0b, xb, n);

  // ---- layer 2 ----  (xb -> B1 -> out)
  aggregate_bf16<<<agg_grid, 256, 0, stream>>>(xb, rowptr, srt, (unsigned short*)B1, n);
  mlp_kernel<0><<<mlp_grid, 512, 0, stream>>>(B1, wb16 + 4096, b1a, wb16 + 6144, b1b, out, n);
}